// Round 2
// baseline (468.527 us; speedup 1.0000x reference)
//
#include <hip/hip_runtime.h>
#include <hip/hip_bf16.h>
#include <math.h>

#define NN    128          // total nodes
#define BS    64           // samples per block == threads (main & pilot)
#define G     8            // nodes per group (independent within a level)
#define CH    4            // groups per chunk; z prefetch depth = CH groups
#define SCAP  2048         // zidx schedule capacity (slots)
#define SCAPS 1024         // LDS schedule build capacity (worst: 128 levels * 8)
#define ROOTF (1 << 30)

// ws layout:
//   [0,     2048)   float4 wf[128]   {w0, w1, b, sigma}
//   [2048,  2560)   int    pk[128]   p0 | p1<<8 | root<<16
//   [4096, 12288)   int    zidx[2048] schedule codes: node | root<<30 (tail-padded)
//   [12288, 12292)  int    ngroups
//   [16384, +128K)  float  pilot_out[128][256]

// ---------------------------------------------------------------- prep
__global__ __launch_bounds__(128) void prep_kernel(
    const float* __restrict__ W, const float* __restrict__ b,
    const float* __restrict__ pm, const int* __restrict__ pidx,
    float4* __restrict__ wf, int* __restrict__ pk,
    int* __restrict__ zidx, int* __restrict__ ngp)
{
    __shared__ int dep[NN], cnt[NN], lst[NN + 1], sidx[SCAPS];
    __shared__ int mx, total;
    const int i = threadIdx.x;                 // == node id
    float m0 = pm[2 * i], m1 = pm[2 * i + 1];
    int   p0 = pidx[2 * i], p1 = pidx[2 * i + 1];
    int   rt = (m0 == 0.0f && m1 == 0.0f) ? 1 : 0;
    wf[i] = make_float4(W[2 * i] * m0, W[2 * i + 1] * m1, b[i], 0.0f);
    pk[i] = p0 | (p1 << 8) | (rt << 16);

    dep[i] = 0; cnt[i] = 0;
    if (i == 0) { mx = 0; }
    __syncthreads();
    // parallel fixpoint for longest-path depth (monotone, converges in depth iters)
    for (int it = 0; it < NN; ++it) {
        int nd = rt ? 0 : 1 + max(dep[p0], dep[p1]);
        int ch = (nd != dep[i]);
        dep[i] = nd;
        if (__syncthreads_count(ch) == 0) break;
    }
    int l = dep[i];
    atomicMax(&mx, l);
    int r = atomicAdd(&cnt[l], 1);
    __syncthreads();
    if (i == 0) {
        int acc = 0;
        for (int q = 0; q <= mx; ++q) { lst[q] = acc; acc += (cnt[q] + G - 1) & ~(G - 1); }
        lst[mx + 1] = acc;
        total = acc;
        ngp[0] = acc / G;
    }
    __syncthreads();
    int code = i | (rt ? ROOTF : 0);
    sidx[lst[l] + r] = code;
    if (r == 0) {   // rank-0 node of each level fills that level's pad slots (idempotent recompute)
        int lend = lst[l] + ((cnt[l] + G - 1) & ~(G - 1));
        for (int q = lst[l] + cnt[l]; q < lend; ++q) sidx[q] = code;
    }
    __syncthreads();
    int tl = total;
    for (int k = i; k < SCAP; k += NN) zidx[k] = sidx[k < tl ? k : tl - 1];
}

// ---------------------------------------------------------------- pilot
// Noiseless pass over 256 calibration samples; 4 blocks x 64 samples.
__global__ __launch_bounds__(64) void pilot_kernel(
    const float4* __restrict__ wf, const int* __restrict__ pk,
    const int* __restrict__ zidx, const int* __restrict__ ngp,
    const float* __restrict__ root_pilot, float* __restrict__ pilot_out, int CAL)
{
    __shared__ float vals[NN * BS];            // 32 KB
    const int tid = threadIdx.x;
    const int jj  = blockIdx.x * BS + tid;
    const int ng  = ngp[0];
    for (int g = 0; g < ng; ++g) {
        int cd[G], pkv[G]; float4 w[G];
        #pragma unroll
        for (int u = 0; u < G; ++u) cd[u] = zidx[g * G + u];
        #pragma unroll
        for (int u = 0; u < G; ++u) { int n = cd[u] & 0xffff; pkv[u] = pk[n]; w[u] = wf[n]; }
        #pragma unroll
        for (int u = 0; u < G; ++u) {
            int n = cd[u] & 0xffff;
            float v;
            if (pkv[u] & 0x10000) {
                v = root_pilot[(size_t)n * CAL + jj];
            } else {
                int q0 = pkv[u] & 0xff, q1 = (pkv[u] >> 8) & 0xff;
                float a = vals[q0 * BS + (tid ^ (q0 & 31))];
                float c = vals[q1 * BS + (tid ^ (q1 & 31))];
                v = fmaxf(fmaf(w[u].x, a, fmaf(w[u].y, c, w[u].z)), 0.0f);
            }
            if (!isfinite(v)) v = 0.0f;
            vals[n * BS + (tid ^ (n & 31))] = v;
            pilot_out[(size_t)n * CAL + jj] = v;   // pads rewrite same value: idempotent
        }
    }
}

// ---------------------------------------------------------------- quant
// Bitonic sort of CAL=256 values per node; sigma -> wf[node].w
__global__ __launch_bounds__(256) void quant_kernel(
    const float* __restrict__ pilot, float4* __restrict__ wf, int CAL)
{
    __shared__ float s[256];
    const int tid = threadIdx.x;
    const int node = blockIdx.x;
    s[tid] = pilot[(size_t)node * CAL + tid];
    __syncthreads();
    for (int k = 2; k <= 256; k <<= 1) {
        for (int jj = k >> 1; jj > 0; jj >>= 1) {
            int ixj = tid ^ jj;
            if (ixj > tid) {
                float a = s[tid], bv = s[ixj];
                bool up = ((tid & k) == 0);
                if ((a > bv) == up) { s[tid] = bv; s[ixj] = a; }
            }
            __syncthreads();
        }
    }
    if (tid == 0) {
        float q25 = s[63]  + 0.75f * (s[64]  - s[63]);
        float q75 = s[191] + 0.25f * (s[192] - s[191]);
        ((float*)&wf[node])[3] = 0.1f * fmaxf(q75 - q25, 1e-6f);
    }
}

// ---------------------------------------------------------------- main
// One chunk = CH groups of G nodes. All register-array indices are literal
// (chunk body inlined twice for ping-pong parity). zbuf ring gives z loads a
// CH-group (~4) lead; params double-buffered one group ahead; codes one chunk
// ahead. Tail chunks recompute the last real node (idempotent).
__device__ __forceinline__ void do_chunk(
    int gg, int (&ccur)[CH][G], int (&cnxt)[CH][G],
    int (&pkb)[2][G], float4 (&wfb)[2][G], float (&zbuf)[CH][G],
    const int* __restrict__ zidx, const int* __restrict__ pk,
    const float4* __restrict__ wf,
    const float* __restrict__ root_main, const float* __restrict__ z,
    size_t NS, size_t j, float* vals, int tid)
{
    // codes for chunk gg+1
    #pragma unroll
    for (int s = 0; s < CH; ++s)
        #pragma unroll
        for (int u = 0; u < G; ++u)
            cnxt[s][u] = zidx[(gg + 1) * CH * G + s * G + u];

    #pragma unroll
    for (int s = 0; s < CH; ++s) {
        // params for group g+1 (parity (s+1)&1)
        #pragma unroll
        for (int u = 0; u < G; ++u) {
            int cN = (s < CH - 1) ? ccur[s + 1][u] : cnxt[0][u];
            int n  = cN & 0xffff;
            pkb[(s + 1) & 1][u] = pk[n];
            wfb[(s + 1) & 1][u] = wf[n];
        }
        // consume this group's z, then refill slot with group (gg+1)*CH+s
        float zv[G];
        #pragma unroll
        for (int u = 0; u < G; ++u) zv[u] = zbuf[s][u];
        #pragma unroll
        for (int u = 0; u < G; ++u) {
            int c = cnxt[s][u];
            const float* base = (c & ROOTF) ? root_main : z;
            zbuf[s][u] = base[(size_t)(c & 0xffff) * NS + j];
        }
        // compute group g = gg*CH+s
        #pragma unroll
        for (int u = 0; u < G; ++u) {
            int   pkv = pkb[s & 1][u];
            float4 w  = wfb[s & 1][u];
            float v;
            if (pkv & 0x10000) {
                v = zv[u];
            } else {
                int q0 = pkv & 0xff, q1 = (pkv >> 8) & 0xff;
                float a = vals[q0 * BS + (tid ^ (q0 & 31))];
                float c2 = vals[q1 * BS + (tid ^ (q1 & 31))];
                v = fmaxf(fmaf(w.x, a, fmaf(w.y, c2, w.z)), 0.0f) + w.w * zv[u];
            }
            if (!isfinite(v)) v = 0.0f;
            int n = ccur[s][u] & 0xffff;
            vals[n * BS + (tid ^ (n & 31))] = v;
        }
    }
}

__global__ __launch_bounds__(64) void main_kernel(
    const float4* __restrict__ wf, const int* __restrict__ pk,
    const int* __restrict__ zidx, const int* __restrict__ ngp,
    const float* __restrict__ root_main, const float* __restrict__ z,
    const int* __restrict__ chosen, float* __restrict__ out, size_t NS)
{
    __shared__ float vals[NN * BS];            // 32 KB -> 5 blocks/CU
    const int tid = threadIdx.x;
    const size_t j = (size_t)blockIdx.x * BS + tid;
    const int ng  = ngp[0];
    const int ngc = (ng + CH - 1) / CH;        // chunks of real work

    int    codesA[CH][G], codesB[CH][G];
    int    pkb[2][G];
    float4 wfb[2][G];
    float  zbuf[CH][G];

    // prologue: codes chunk 0, z for groups 0..CH-1, params group 0
    #pragma unroll
    for (int s = 0; s < CH; ++s)
        #pragma unroll
        for (int u = 0; u < G; ++u)
            codesA[s][u] = zidx[s * G + u];
    #pragma unroll
    for (int s = 0; s < CH; ++s)
        #pragma unroll
        for (int u = 0; u < G; ++u) {
            int c = codesA[s][u];
            const float* base = (c & ROOTF) ? root_main : z;
            zbuf[s][u] = base[(size_t)(c & 0xffff) * NS + j];
        }
    #pragma unroll
    for (int u = 0; u < G; ++u) {
        int n = codesA[0][u] & 0xffff;
        pkb[0][u] = pk[n];
        wfb[0][u] = wf[n];
    }

    // run chunks in ping-pong pairs; over-run past ngc is idempotent
    for (int gg = 0; gg < ngc; gg += 2) {
        do_chunk(gg,     codesA, codesB, pkb, wfb, zbuf, zidx, pk, wf, root_main, z, NS, j, vals, tid);
        do_chunk(gg + 1, codesB, codesA, pkb, wfb, zbuf, zidx, pk, wf, root_main, z, NS, j, vals, tid);
    }

    __syncthreads();
    // epilogue: transpose to out[sample][k] via float4 stores
    float4* out4 = (float4*)(out + (size_t)blockIdx.x * BS * 64);
    #pragma unroll
    for (int it = 0; it < 16; ++it) {
        int c  = it * BS + tid;        // float4 chunk id, 0..1023
        int s  = c >> 4;               // local sample
        int k0 = (c & 15) << 2;        // chosen base
        int n0 = chosen[k0], n1 = chosen[k0 + 1], n2 = chosen[k0 + 2], n3 = chosen[k0 + 3];
        float4 o;
        o.x = vals[n0 * BS + (s ^ (n0 & 31))];
        o.y = vals[n1 * BS + (s ^ (n1 & 31))];
        o.z = vals[n2 * BS + (s ^ (n2 & 31))];
        o.w = vals[n3 * BS + (s ^ (n3 & 31))];
        out4[c] = o;
    }
}

extern "C" void kernel_launch(void* const* d_in, const int* in_sizes, int n_in,
                              void* d_out, int out_size, void* d_ws, size_t ws_size,
                              hipStream_t stream) {
    const float* W          = (const float*)d_in[1];
    const float* b          = (const float*)d_in[2];
    const float* root_pilot = (const float*)d_in[3];
    const float* root_main  = (const float*)d_in[4];
    const float* z          = (const float*)d_in[5];
    const float* pm         = (const float*)d_in[6];
    const int*   pidx       = (const int*)d_in[7];
    const int*   chosen     = (const int*)d_in[9];
    float* out = (float*)d_out;

    const size_t NS  = (size_t)in_sizes[4] / NN;   // 262144
    const int    CAL = in_sizes[3] / NN;           // 256

    char* ws = (char*)d_ws;
    float4* wf    = (float4*)ws;
    int*    pk    = (int*)(ws + 2048);
    int*    zidx  = (int*)(ws + 4096);
    int*    ngp   = (int*)(ws + 12288);
    float*  pilot = (float*)(ws + 16384);

    prep_kernel <<<1, 128, 0, stream>>>(W, b, pm, pidx, wf, pk, zidx, ngp);
    pilot_kernel<<<CAL / BS, BS, 0, stream>>>(wf, pk, zidx, ngp, root_pilot, pilot, CAL);
    quant_kernel<<<NN, 256, 0, stream>>>(pilot, wf, CAL);
    main_kernel <<<(int)(NS / BS), BS, 0, stream>>>(wf, pk, zidx, ngp, root_main, z, chosen, out, NS);
}

// Round 3
// 354.518 us; speedup vs baseline: 1.3216x; 1.3216x over previous
//
#include <hip/hip_runtime.h>
#include <hip/hip_fp16.h>
#include <math.h>

#define NN   128           // total nodes
#define BS   64            // samples per block == threads == one wave
#define SCAP 1056          // schedule slot capacity (worst case 1024 + overshoot)
#define RT_F 0x10000       // root flag in pcode

// fp16 LDS swizzle: element (node n, lane t) at n*64 + (t ^ ((n&15)<<1)).
// bank = ((t>>1) ^ (n&15)) & 31 -> compute phase (n fixed): 2-way, free;
// epilogue transpose (t fixed-ish, n varies): conflict-free.
#define IDX(n,t) ((n)*BS + ((t) ^ (((n)&15)<<1)))

// ws layout:
//   [0,     16896)  float4 wtab[SCAP]   {w0,w1,b,sigma} slot-ordered
//   [20480, 24704)  int    pcode[SCAP]  p0 | p1<<8 | root<<16 | node<<24
//   [24704, 25216)  int    slotmap[128] node -> canonical slot
//   [25216, 25220)  int    S (padded slot count, multiple of 32)
//   [28672, +128K)  float  pilot_out[128][256]

// ---------------------------------------------------------------- prep
// Greedy width-8 list scheduler: group g takes (up to) the first 8 nodes whose
// parents are in strictly earlier groups. Node ids are topological (parents <
// child), so >=1 node is scheduled per iteration -> terminates. Unfilled slots
// become replicas of node 0 (always a root; sigma-free, idempotent rewrite).
__global__ __launch_bounds__(128) void prep_kernel(
    const float* __restrict__ W, const float* __restrict__ b,
    const float* __restrict__ pm, const int* __restrict__ pidx,
    float4* __restrict__ wtab, int* __restrict__ pcode,
    int* __restrict__ slotmap, int* __restrict__ ngp)
{
    __shared__ int grp[NN], slot[NN], wcnt[2];
    __shared__ int nassigned, gdone, gfin;
    const int i = threadIdx.x, w = i >> 6, lane = i & 63;
    const float m0 = pm[2*i], m1 = pm[2*i+1];
    const int   p0 = pidx[2*i], p1 = pidx[2*i+1];
    const int   rt = (m0 == 0.0f && m1 == 0.0f) ? 1 : 0;
    grp[i] = -1; slot[i] = 0;
    if (i == 0) { nassigned = 0; gdone = 0; gfin = 0; }
    __syncthreads();
    for (int g = 0; g < NN; ++g) {
        int ready = (grp[i] < 0) && (rt || (grp[p0] >= 0 && grp[p1] >= 0));
        unsigned long long mask = __ballot(ready);
        if (lane == 0) wcnt[w] = __popcll(mask);
        __syncthreads();
        int base = w ? wcnt[0] : 0;
        int r = base + __popcll(mask & ((1ull << lane) - 1ull));
        if (ready && r < 8) { grp[i] = g; slot[i] = g*8 + r; }
        if (i == 0) {
            nassigned += min(wcnt[0] + wcnt[1], 8);
            if (nassigned >= NN) { gdone = 1; gfin = g; }
        }
        __syncthreads();
        if (gdone) break;
    }
    const int S0 = 8 * (gfin + 1);
    const int S  = (S0 + 31) & ~31;
    // default-fill every slot with a node-0 replica
    for (int k = i; k < SCAP; k += NN) {
        pcode[k] = RT_F;                       // p0=0,p1=0,root=1,node=0
        wtab[k]  = make_float4(0.f, 0.f, 0.f, 0.f);
    }
    __threadfence_block();
    __syncthreads();
    // canonical entries overwrite replicas
    pcode[slot[i]] = p0 | (p1 << 8) | (rt << 16) | (i << 24);
    wtab[slot[i]]  = make_float4(W[2*i]*m0, W[2*i+1]*m1, b[i], 0.f);
    slotmap[i] = slot[i];
    if (i == 0) ngp[0] = S;
}

// ---------------------------------------------------------------- pilot
// Noiseless calibration pass, 4 blocks x 64 samples. Literal-offset table
// loads; replica slots rewrite identical values (idempotent).
__global__ __launch_bounds__(64) void pilot_kernel(
    const float4* __restrict__ wtab, const int* __restrict__ pcode,
    const int* __restrict__ ngp, const float* __restrict__ root_pilot,
    float* __restrict__ pilot_out, int CAL)
{
    __shared__ _Float16 vals[NN * BS];
    const int tid = threadIdx.x;
    const int jj  = blockIdx.x * BS + tid;
    const int S   = ngp[0];
    for (int s0 = 0; s0 < S; s0 += 8) {
        int pc[8]; float4 wv[8];
        #pragma unroll
        for (int u = 0; u < 8; ++u) pc[u] = pcode[s0 + u];
        #pragma unroll
        for (int u = 0; u < 8; ++u) wv[u] = wtab[s0 + u];
        #pragma unroll
        for (int u = 0; u < 8; ++u) {
            int node = (pc[u] >> 24) & 0xff;
            float v;
            if (pc[u] & RT_F) {
                v = root_pilot[node * CAL + jj];
            } else {
                int q0 = pc[u] & 0xff, q1 = (pc[u] >> 8) & 0xff;
                float a = (float)vals[IDX(q0, tid)];
                float c = (float)vals[IDX(q1, tid)];
                v = fmaxf(fmaf(wv[u].x, a, fmaf(wv[u].y, c, wv[u].z)), 0.0f);
            }
            if (!isfinite(v)) v = 0.0f;
            vals[IDX(node, tid)] = (_Float16)v;
            pilot_out[node * CAL + jj] = v;
        }
    }
}

// ---------------------------------------------------------------- quant
// Bitonic sort of CAL=256 pilot values per node; sigma -> wtab[slot].w
__global__ __launch_bounds__(256) void quant_kernel(
    const float* __restrict__ pilot, const int* __restrict__ slotmap,
    float4* __restrict__ wtab, int CAL)
{
    __shared__ float s[256];
    const int tid = threadIdx.x;
    const int node = blockIdx.x;
    s[tid] = pilot[(size_t)node * CAL + tid];
    __syncthreads();
    for (int k = 2; k <= 256; k <<= 1) {
        for (int jj = k >> 1; jj > 0; jj >>= 1) {
            int ixj = tid ^ jj;
            if (ixj > tid) {
                float a = s[tid], bv = s[ixj];
                bool up = ((tid & k) == 0);
                if ((a > bv) == up) { s[tid] = bv; s[ixj] = a; }
            }
            __syncthreads();
        }
    }
    if (tid == 0) {
        float q25 = s[63]  + 0.75f * (s[64]  - s[63]);
        float q75 = s[191] + 0.25f * (s[192] - s[191]);
        ((float*)&wtab[slotmap[node]])[3] = 0.1f * fmaxf(q75 - q25, 1e-6f);
    }
}

// ---------------------------------------------------------------- main
__device__ __forceinline__ void mk_chunk(
    int c, int P, float (&zb)[2][16],
    const int* __restrict__ pcode, const float4* __restrict__ wtab,
    const float* __restrict__ root_main, const float* __restrict__ z,
    unsigned NS, size_t j, _Float16* vals, int tid)
{
    const int base = c * 16;
    // prefetch z for slots [base+16, base+32)
    #pragma unroll
    for (int u = 0; u < 16; ++u) {
        int pcN = pcode[base + 16 + u];
        const float* src = (pcN & RT_F) ? root_main : z;
        unsigned node = (unsigned)(pcN >> 24) & 0xffu;
        zb[P ^ 1][u] = src[(size_t)(node * NS) + j];
    }
    // compute slots [base, base+16)
    #pragma unroll
    for (int u = 0; u < 16; ++u) {
        int pc = pcode[base + u];
        float4 wv = wtab[base + u];
        float zv = zb[P][u];
        float v;
        if (pc & RT_F) {
            v = zv;
        } else {
            int q0 = pc & 0xff, q1 = (pc >> 8) & 0xff;
            float a  = (float)vals[IDX(q0, tid)];
            float c2 = (float)vals[IDX(q1, tid)];
            v = fmaxf(fmaf(wv.x, a, fmaf(wv.y, c2, wv.z)), 0.0f) + wv.w * zv;
        }
        if (!isfinite(v)) v = 0.0f;
        int node = (pc >> 24) & 0xff;
        vals[IDX(node, tid)] = (_Float16)v;
    }
}

__global__ __launch_bounds__(64) void main_kernel(
    const float4* __restrict__ wtab, const int* __restrict__ pcode,
    const int* __restrict__ ngp,
    const float* __restrict__ root_main, const float* __restrict__ z,
    const int* __restrict__ chosen, float* __restrict__ out, int NSi)
{
    __shared__ _Float16 vals[NN * BS];     // 16 KB -> 10 blocks/CU
    const int tid = threadIdx.x;
    const size_t j = (size_t)blockIdx.x * BS + tid;
    const unsigned NS = (unsigned)NSi;
    const int S = ngp[0];                   // multiple of 32
    const int nch = S >> 4;                 // even chunk count

    float zb[2][16];
    #pragma unroll
    for (int u = 0; u < 16; ++u) {
        int pc = pcode[u];
        const float* src = (pc & RT_F) ? root_main : z;
        unsigned node = (unsigned)(pc >> 24) & 0xffu;
        zb[0][u] = src[(size_t)(node * NS) + j];
    }

    for (int c = 0; c < nch; c += 2) {
        mk_chunk(c,     0, zb, pcode, wtab, root_main, z, NS, j, vals, tid);
        mk_chunk(c + 1, 1, zb, pcode, wtab, root_main, z, NS, j, vals, tid);
    }

    __syncthreads();   // epilogue reads other lanes' columns (cross-lane in wave)

    // transpose epilogue: out[sample][k], float4 coalesced stores
    float4* out4 = (float4*)(out + (size_t)blockIdx.x * BS * 64);
    #pragma unroll
    for (int it = 0; it < 16; ++it) {
        int cc = it * BS + tid;            // float4 chunk id, 0..1023
        int s  = cc >> 4;                  // local sample
        int k0 = (cc & 15) << 2;           // chosen base
        int n0 = chosen[k0], n1 = chosen[k0+1], n2 = chosen[k0+2], n3 = chosen[k0+3];
        float4 o;
        o.x = (float)vals[IDX(n0, s)];
        o.y = (float)vals[IDX(n1, s)];
        o.z = (float)vals[IDX(n2, s)];
        o.w = (float)vals[IDX(n3, s)];
        out4[cc] = o;
    }
}

extern "C" void kernel_launch(void* const* d_in, const int* in_sizes, int n_in,
                              void* d_out, int out_size, void* d_ws, size_t ws_size,
                              hipStream_t stream) {
    const float* W          = (const float*)d_in[1];
    const float* b          = (const float*)d_in[2];
    const float* root_pilot = (const float*)d_in[3];
    const float* root_main  = (const float*)d_in[4];
    const float* z          = (const float*)d_in[5];
    const float* pm         = (const float*)d_in[6];
    const int*   pidx       = (const int*)d_in[7];
    const int*   chosen     = (const int*)d_in[9];
    float* out = (float*)d_out;

    const int NS  = in_sizes[4] / NN;   // 262144
    const int CAL = in_sizes[3] / NN;   // 256

    char* ws = (char*)d_ws;
    float4* wtab    = (float4*)ws;
    int*    pcode   = (int*)(ws + 20480);
    int*    slotmap = (int*)(ws + 24704);
    int*    ngp     = (int*)(ws + 25216);
    float*  pilot   = (float*)(ws + 28672);

    prep_kernel <<<1, 128, 0, stream>>>(W, b, pm, pidx, wtab, pcode, slotmap, ngp);
    pilot_kernel<<<CAL / BS, BS, 0, stream>>>(wtab, pcode, ngp, root_pilot, pilot, CAL);
    quant_kernel<<<NN, 256, 0, stream>>>(pilot, slotmap, wtab, CAL);
    main_kernel <<<NS / BS, BS, 0, stream>>>(wtab, pcode, ngp, root_main, z, chosen, out, NS);
}